// Round 16
// baseline (108.342 us; speedup 1.0000x reference)
//
#include <hip/hip_runtime.h>
#include <hip/hip_bf16.h>
#include <cmath>

typedef __bf16 bf16;
typedef __attribute__((ext_vector_type(8))) __bf16 bf16x8;
typedef __attribute__((ext_vector_type(4))) __bf16 bf16x4;
typedef __attribute__((ext_vector_type(4))) float f32x4;
typedef __attribute__((ext_vector_type(16))) float f32x16;
typedef unsigned int u32;

constexpr int S  = 2048;
constexpr int E  = 1024;
constexpr int H  = 16;
constexpr int D  = 64;
constexpr int B  = 2;
constexpr int M  = B * S;       // 4096 rows
constexpr int N3 = 3 * E;       // 3072
constexpr int NROWS = B * H * S; // 65536
constexpr int NSLOT = 40;       // graded slots per bh (max-8-tile split)

// graded K-split, 64-key tiles, max 8 tiles/block: chunk c has nt=2c+2 tiles
// (causal), P(c)=ceil(nt/8) partials, 40 slots/bh, LPT dispatch order.
__constant__ int P_tab_d[16] = {1,1,1,1,2,2,2,2,3,3,3,3,4,4,4,4};
__constant__ int S_tab_d[16] = {0,1,2,3,4,6,8,10,12,15,18,21,24,28,32,36};
// slots ordered by tile count descending (8s, 7s, 6s, 5s, 4, 2)
__constant__ int c_ord_d[NSLOT] = {3,7,7,10,11,11,11,14,14,15,15,15,15,
                                   6,6,9,9,10,10,12,12,13,13,13,13,14,14,
                                   2,5,5,8,8,8,9,12,12, 4,4, 1, 0};
__constant__ int p_ord_d[NSLOT] = {0,0,1,2,0,1,2,1,3,0,1,2,3,
                                   0,1,1,2,0,1,1,3,0,1,2,3,0,2,
                                   0,0,1,0,1,2,0,0,2, 0,1, 0, 0};

static __device__ __forceinline__ void gload16(const void* g, void* l) {
  __builtin_amdgcn_global_load_lds((const __attribute__((address_space(1))) void*)g,
                                   (__attribute__((address_space(3))) void*)l, 16, 0, 0);
}

static __device__ __forceinline__ u32 pack2(float a, float b) {
  union { bf16 h[2]; u32 u; } r;
  r.h[0] = (bf16)a; r.h[1] = (bf16)b;
  return r.u;
}
typedef union { u32 w[4]; bf16x8 v; } FU;

// ---------- fused prep: cvt x->bf16 | W_in^T | W_out^T ----------
__global__ __launch_bounds__(256) void k_prep(
    const float* __restrict__ x, bf16* __restrict__ xb,
    const float* __restrict__ W_in, bf16* __restrict__ wtin,
    const float* __restrict__ W_out, bf16* __restrict__ wtout)
{
  const int bid = blockIdx.x;
  if (bid < 4096) {
    const int i = (bid * 256 + threadIdx.x) * 4;
    const float4 v = *(const float4*)(x + i);
    bf16x4 o = { (bf16)v.x, (bf16)v.y, (bf16)v.z, (bf16)v.w };
    *(bf16x4*)(xb + i) = o;
  } else {
    __shared__ float t[32][33];
    const float* in;
    bf16* out;
    int R, C, bx, by;
    if (bid < 4096 + 3072) {
      const int b = bid - 4096;
      in = W_in; out = wtin; R = E; C = N3;
      bx = b % (N3 / 32); by = b / (N3 / 32);
    } else {
      const int b = bid - 4096 - 3072;
      in = W_out; out = wtout; R = E; C = E;
      bx = b % (E / 32); by = b / (E / 32);
    }
    const int c0 = bx * 32, r0 = by * 32;
    const int tx = threadIdx.x & 31, ty = threadIdx.x >> 5;
    #pragma unroll
    for (int j = 0; j < 32; j += 8)
      t[ty + j][tx] = in[(size_t)(r0 + ty + j) * C + c0 + tx];
    __syncthreads();
    #pragma unroll
    for (int j = 0; j < 32; j += 8)
      out[(size_t)(c0 + ty + j) * R + r0 + tx] = (bf16)t[tx][ty + j];
  }
}

// ---------- GEMM (unchanged from round 6/9/10/13, verified) ----------
template<int EPI>
__global__ __launch_bounds__(256) void k_gemm(
    const bf16* __restrict__ A, const bf16* __restrict__ Bt,
    const float* __restrict__ bias, float* __restrict__ outF,
    bf16* __restrict__ oQ, bf16* __restrict__ oK, bf16* __restrict__ oV,
    int Kdim, int Nn)
{
  __shared__ __align__(16) char smem[65536];
  const int tid = threadIdx.x;
  const int lane = tid & 63, w = tid >> 6;
  const int lane15 = lane & 15, quad = lane >> 4;
  const int wm = w >> 1, wn = w & 1;

  const int nbx = Nn >> 7;
  const int nwg = gridDim.x;
  const int bid = blockIdx.x;
  const int swz = (bid & 7) * (nwg >> 3) + (bid >> 3);
  const int bn0 = (swz % nbx) * 128;
  const int bm0 = (swz / nbx) * 128;

  const int so0 = w * 1024 + lane * 16;
  int srow[4], slk[4];
  #pragma unroll
  for (int p = 0; p < 4; ++p) {
    const int o = p * 4096 + so0;
    const int row = o >> 7, cbyte = o & 127;
    srow[p] = row;
    slk[p] = (cbyte ^ ((row & 7) << 4)) >> 1;
  }

  f32x4 acc[4][4] = {};
  const int nkt = Kdim >> 6;

  #pragma unroll
  for (int p = 0; p < 4; ++p) {
    gload16(A  + (size_t)(bm0 + srow[p]) * Kdim + slk[p], smem +         p * 4096 + w * 1024);
    gload16(Bt + (size_t)(bn0 + srow[p]) * Kdim + slk[p], smem + 32768 + p * 4096 + w * 1024);
  }

  #pragma unroll 1
  for (int kt = 0; kt < nkt; ++kt) {
    const int cur = kt & 1;
    __builtin_amdgcn_s_barrier();
    if (kt + 1 < nkt) {
      const int k0 = (kt + 1) << 6;
      const int nb = (cur ^ 1) * 16384;
      #pragma unroll
      for (int p = 0; p < 4; ++p) {
        gload16(A  + (size_t)(bm0 + srow[p]) * Kdim + k0 + slk[p],
                smem + nb +         p * 4096 + w * 1024);
        gload16(Bt + (size_t)(bn0 + srow[p]) * Kdim + k0 + slk[p],
                smem + nb + 32768 + p * 4096 + w * 1024);
      }
      asm volatile("s_waitcnt vmcnt(8)" ::: "memory");
    } else {
      asm volatile("s_waitcnt vmcnt(0)" ::: "memory");
    }
    __builtin_amdgcn_s_barrier();

    const char* cA = smem + cur * 16384;
    const char* cB = smem + 32768 + cur * 16384;
    #pragma unroll
    for (int kk = 0; kk < 2; ++kk) {
      bf16x8 af[4], bfr[4];
      #pragma unroll
      for (int f = 0; f < 4; ++f) {
        const int ra = wm * 64 + f * 16 + lane15;
        af[f] = *(const bf16x8*)(cA + ra * 128 +
                 ((kk * 64 + (quad << 4)) ^ ((ra & 7) << 4)));
        const int rb = wn * 64 + f * 16 + lane15;
        bfr[f] = *(const bf16x8*)(cB + rb * 128 +
                 ((kk * 64 + (quad << 4)) ^ ((rb & 7) << 4)));
      }
      #pragma unroll
      for (int i = 0; i < 4; ++i)
        #pragma unroll
        for (int j = 0; j < 4; ++j)
          acc[i][j] = __builtin_amdgcn_mfma_f32_16x16x32_bf16(af[i], bfr[j], acc[i][j], 0, 0, 0);
    }
  }

  if constexpr (EPI == 1) {
    #pragma unroll
    for (int i = 0; i < 4; ++i)
      #pragma unroll
      for (int j = 0; j < 4; ++j) {
        const int n = bn0 + wn * 64 + j * 16 + lane15;
        const float bv = bias[n];
        #pragma unroll
        for (int r = 0; r < 4; ++r) {
          const int m = bm0 + wm * 64 + i * 16 + quad * 4 + r;
          outF[(size_t)m * E + n] = acc[i][j][r] + bv;
        }
      }
  } else {
    const int which = bn0 >> 10;
    const int b  = bm0 >> 11;
    const int s0 = bm0 & (S - 1);
    const int cn0 = bn0 & (E - 1);
    if (which < 2) {
      __builtin_amdgcn_s_barrier();
      char* lC = smem;
      #pragma unroll
      for (int j = 0; j < 4; ++j) {
        const int n_loc = wn * 64 + j * 16 + lane15;
        const float bv = bias[bn0 + n_loc];
        #pragma unroll
        for (int i = 0; i < 4; ++i)
          #pragma unroll
          for (int r = 0; r < 4; ++r) {
            const int m_loc = wm * 64 + i * 16 + quad * 4 + r;
            *(bf16*)(lC + m_loc * 256 + ((n_loc * 2) ^ ((m_loc & 7) << 4))) =
                (bf16)(acc[i][j][r] + bv);
          }
      }
      __builtin_amdgcn_s_barrier();
      const int h0 = cn0 >> 6;
      #pragma unroll
      for (int it = 0; it < 8; ++it) {
        const int cch = w * 64 + it * 8 + (lane >> 3);
        const int m_loc = cch >> 1, hh = cch & 1, piece = lane & 7;
        const bf16x8 vv = *(const bf16x8*)(lC + m_loc * 256 +
                          ((hh * 128 + piece * 16) ^ ((m_loc & 7) << 4)));
        if (which == 0) {
          *(bf16x8*)(oQ + ((size_t)(b * H + h0 + hh) * S + s0 + m_loc) * D + piece * 8) = vv;
        } else {
          const size_t hb = (size_t)(b * H + h0 + hh) * S * D;
          const int tile = (s0 + m_loc) >> 6;
          const int row = m_loc & 63;
          *(bf16x8*)(oK + hb + (size_t)tile * 4096 + (piece >> 1) * 1024 +
                     (row >> 5) * 512 + (32 * (piece & 1) + (row & 31)) * 8) = vv;
        }
      }
    } else {
      #pragma unroll
      for (int j = 0; j < 4; ++j) {
        const int n_loc = wn * 64 + j * 16 + lane15;
        const int cn = cn0 + n_loc;
        const int hv = cn >> 6, dd = cn & 63;
        const float bv = bias[bn0 + n_loc];
        const size_t hb = (size_t)(b * H + hv) * S * D;
        #pragma unroll
        for (int i = 0; i < 4; ++i) {
          const int scol_g = s0 + wm * 64 + i * 16 + quad * 4;
          const int vtile = scol_g >> 6;
          const int cg = (scol_g & 63) >> 3;
          bf16x4 pk = { (bf16)(acc[i][j][0] + bv), (bf16)(acc[i][j][1] + bv),
                        (bf16)(acc[i][j][2] + bv), (bf16)(acc[i][j][3] + bv) };
          *(bf16x4*)(oV + hb + (size_t)vtile * 4096 + (cg >> 1) * 1024 +
                     (dd >> 5) * 512 + (32 * (cg & 1) + (dd & 31)) * 8 +
                     (quad & 1) * 4) = pk;
        }
      }
    }
  }
}

// ---------- flash attention: round-15 inner loop, max-8 graded split ----------
// KVBLK=64, barrier-free, fragment-major K/V, defer-max THR=64. Grid (32, 40):
// 1280 blocks, max 8 tiles each, LPT order -> backfill smooths the tail.
__global__ __launch_bounds__(256, 4) void k_attn(
    const bf16* __restrict__ Qb, const bf16* __restrict__ Kf, const bf16* __restrict__ Vf,
    bf16* __restrict__ pO, float* __restrict__ pM, float* __restrict__ pL,
    const int* __restrict__ cmask)
{
  __shared__ float corr_lds[4][32];
  __shared__ float lrow_lds[4][32];

  const int tid = threadIdx.x, lane = tid & 63, w = tid >> 6;
  const int h = lane >> 5, q31 = lane & 31;
  const int bh = blockIdx.x;
  const int yy = blockIdx.y;
  const int c  = c_ord_d[yy];
  const int p  = p_ord_d[yy];
  const int Pc = P_tab_d[c];
  const int sslot = S_tab_d[c] + p;
  const int causal = cmask[0];
  const float S2 = 0.18033688011112042f;  // (1/sqrt(D)) * log2(e)

  const bf16* Qh = Qb + (size_t)bh * S * D;
  const bf16* Kh = Kf + (size_t)bh * S * D;
  const bf16* Vh = Vf + (size_t)bh * S * D;

  const int nt = causal ? (2 * c + 2) : (S / 64);
  const int t0 = (p * nt) / Pc;
  const int t1 = ((p + 1) * nt) / Pc;
  const int q0w = c * 128 + 32 * w;
  const int qg  = q0w + q31;
  const int t1w = causal ? min(t1, ((q0w + 31) >> 6) + 1) : t1;

  bf16x8 qf[4];
  #pragma unroll
  for (int ds = 0; ds < 4; ++ds)
    qf[ds] = *(const bf16x8*)(Qh + (size_t)qg * D + 16 * ds + 8 * h);

  f32x16 o0 = {}, o1 = {};
  float mrun = -INFINITY, lr = 0.f;

  #pragma unroll 1
  for (int t = t0; t < t1w; ++t) {
    const bf16* ktb = Kh + (size_t)t * 4096;
    const bf16* vtb = Vh + (size_t)t * 4096;

    bf16x8 kf0[4], kf1[4];
    #pragma unroll
    for (int ds = 0; ds < 4; ++ds) {
      kf0[ds] = *(const bf16x8*)(ktb + ds * 1024 +       lane * 8);
      kf1[ds] = *(const bf16x8*)(ktb + ds * 1024 + 512 + lane * 8);
    }

    f32x16 s0v = {}, s1v = {};
    __builtin_amdgcn_s_setprio(1);
    #pragma unroll
    for (int ds = 0; ds < 4; ++ds) {
      s0v = __builtin_amdgcn_mfma_f32_32x32x16_bf16(kf0[ds], qf[ds], s0v, 0, 0, 0);
      s1v = __builtin_amdgcn_mfma_f32_32x32x16_bf16(kf1[ds], qf[ds], s1v, 0, 0, 0);
    }
    __builtin_amdgcn_s_setprio(0);

    if (causal && (64 * t + 63 > q0w)) {
      #pragma unroll
      for (int rr = 0; rr < 16; ++rr) {
        const int kg = 64 * t + (rr & 3) + 8 * (rr >> 2) + 4 * h;
        if (kg > qg)      s0v[rr] = -INFINITY;
        if (kg + 32 > qg) s1v[rr] = -INFINITY;
      }
    }

    float a8[8];
    #pragma unroll
    for (int i = 0; i < 8; ++i)
      a8[i] = fmaxf(fmaxf(s0v[i], s0v[i + 8]), fmaxf(s1v[i], s1v[i + 8]));
    float tmax = fmaxf(fmaxf(fmaxf(a8[0], a8[1]), fmaxf(a8[2], a8[3])),
                       fmaxf(fmaxf(a8[4], a8[5]), fmaxf(a8[6], a8[7])));
    tmax = fmaxf(tmax, __shfl_xor(tmax, 32, 64));

    // T13 defer-max: skip rescale while max grows by < 64 score units (e^8)
    const bool nogrow = __all(tmax <= mrun + 64.f);
    const float mnew = nogrow ? mrun : fmaxf(mrun, tmax);
    float corrf = 1.f;
    if (!nogrow) {
      corrf = __builtin_amdgcn_exp2f((mrun - mnew) * S2);
      corr_lds[w][q31] = corrf;
    }
    const float msc = mnew * S2;

    #pragma unroll
    for (int rr = 0; rr < 16; ++rr) {
      s0v[rr] = __builtin_amdgcn_exp2f(__builtin_fmaf(s0v[rr], S2, -msc));
      s1v[rr] = __builtin_amdgcn_exp2f(__builtin_fmaf(s1v[rr], S2, -msc));
    }

    float b8[8];
    #pragma unroll
    for (int i = 0; i < 8; ++i)
      b8[i] = (s0v[i] + s0v[i + 8]) + (s1v[i] + s1v[i + 8]);
    float psum = ((b8[0] + b8[1]) + (b8[2] + b8[3])) + ((b8[4] + b8[5]) + (b8[6] + b8[7]));
    psum += __shfl_xor(psum, 32, 64);
    lr = lr * corrf + psum;
    mrun = mnew;

    u32 pk[8][2];
    #pragma unroll
    for (int jj = 0; jj < 4; ++jj) {
      pk[jj][0]     = pack2(s0v[4 * jj],     s0v[4 * jj + 1]);
      pk[jj][1]     = pack2(s0v[4 * jj + 2], s0v[4 * jj + 3]);
      pk[jj + 4][0] = pack2(s1v[4 * jj],     s1v[4 * jj + 1]);
      pk[jj + 4][1] = pack2(s1v[4 * jj + 2], s1v[4 * jj + 3]);
    }

    if (!nogrow) {
      #pragma unroll
      for (int j = 0; j < 4; ++j) {
        const f32x4 cv = *(const f32x4*)&corr_lds[w][8 * j + 4 * h];
        #pragma unroll
        for (int sr = 0; sr < 4; ++sr) {
          o0[4 * j + sr] *= cv[sr];
          o1[4 * j + sr] *= cv[sr];
        }
      }
    }

    __builtin_amdgcn_s_setprio(1);
    #pragma unroll
    for (int ks = 0; ks < 4; ++ks) {
      u32 a0 = pk[2 * ks][0], b0 = pk[2 * ks + 1][0];
      u32 a1 = pk[2 * ks][1], b1 = pk[2 * ks + 1][1];
      asm volatile("v_permlane32_swap_b32 %0, %1" : "+v"(a0), "+v"(b0));
      asm volatile("v_permlane32_swap_b32 %0, %1" : "+v"(a1), "+v"(b1));
      FU f; f.w[0] = a0; f.w[1] = a1; f.w[2] = b0; f.w[3] = b1;
      const bf16x8 vf0 = *(const bf16x8*)(vtb + ks * 1024 +       lane * 8);
      const bf16x8 vf1 = *(const bf16x8*)(vtb + ks * 1024 + 512 + lane * 8);
      o0 = __builtin_amdgcn_mfma_f32_32x32x16_bf16(f.v, vf0, o0, 0, 0, 0);
      o1 = __builtin_amdgcn_mfma_f32_32x32x16_bf16(f.v, vf1, o1, 0, 0, 0);
    }
    __builtin_amdgcn_s_setprio(0);
  }  // t

  const size_t slotbase = ((size_t)bh * NSLOT + sslot) * 128;
  if (h == 0) {
    pM[slotbase + 32 * w + q31] = mrun;
    pL[slotbase + 32 * w + q31] = lr;
  }
  lrow_lds[w][q31] = lr;
  bf16* po = pO + slotbase * D;
  #pragma unroll
  for (int j = 0; j < 4; ++j) {
    const f32x4 lv = *(const f32x4*)&lrow_lds[w][8 * j + 4 * h];
    #pragma unroll
    for (int sr = 0; sr < 4; ++sr) {
      const int rr = 4 * j + sr;
      const float inv = lv[sr] > 0.f ? 1.0f / lv[sr] : 0.f;
      const int qloc = 32 * w + (rr & 3) + 8 * (rr >> 2) + 4 * h;
      bf16* dst = po + (size_t)qloc * D;
      dst[q31]      = (bf16)(o0[rr] * inv);
      dst[32 + q31] = (bf16)(o1[rr] * inv);
    }
  }
}

// ---------- combine graded partials (Pc <= 4) -> AO[B,S,E] ----------
__global__ __launch_bounds__(256) void k_combine(
    const bf16* __restrict__ pO, const float* __restrict__ pM,
    const float* __restrict__ pL, bf16* __restrict__ AO)
{
  const float S2 = 0.18033688011112042f;
  const int idx = blockIdx.x * 256 + threadIdx.x;
  const int row = idx >> 3, d0 = (idx & 7) * 8;
  const int bh = row >> 11, s = row & 2047;
  const int c = s >> 7, local = s & 127;
  const int Pc = P_tab_d[c], Sc = S_tab_d[c];

  float mv[4], lv[4];
  float m = -INFINITY;
  #pragma unroll
  for (int p = 0; p < 4; ++p) {
    if (p < Pc) {
      mv[p] = pM[((size_t)bh * NSLOT + Sc + p) * 128 + local];
      lv[p] = pL[((size_t)bh * NSLOT + Sc + p) * 128 + local];
      m = fmaxf(m, mv[p]);
    }
  }
  float wsum = 0.f, wv[4];
  #pragma unroll
  for (int p = 0; p < 4; ++p) {
    wv[p] = 0.f;
    if (p < Pc && lv[p] > 0.f) {
      wv[p] = lv[p] * __builtin_amdgcn_exp2f((mv[p] - m) * S2);
      wsum += wv[p];
    }
  }
  const float inv = 1.0f / wsum;
  float acc[8] = {};
  #pragma unroll
  for (int p = 0; p < 4; ++p) {
    if (p < Pc && wv[p] > 0.f) {
      const bf16x8 a = *(const bf16x8*)(pO +
          (((size_t)bh * NSLOT + Sc + p) * 128 + local) * D + d0);
      #pragma unroll
      for (int i = 0; i < 8; ++i)
        acc[i] += wv[p] * (float)a[i];
    }
  }
  bf16x8 o;
  #pragma unroll
  for (int i = 0; i < 8; ++i)
    o[i] = (bf16)(acc[i] * inv);
  const int bb = row >> 15, hh = (row >> 11) & 15;
  *(bf16x8*)(AO + ((size_t)(bb * S + s)) * E + hh * D + d0) = o;
}

extern "C" void kernel_launch(void* const* d_in, const int* in_sizes, int n_in,
                              void* d_out, int out_size, void* d_ws, size_t ws_size,
                              hipStream_t stream) {
  (void)in_sizes; (void)n_in; (void)out_size; (void)ws_size;
  const float* x     = (const float*)d_in[0];
  const float* W_in  = (const float*)d_in[1];
  const float* b_in  = (const float*)d_in[2];
  const float* W_out = (const float*)d_in[3];
  const float* b_out = (const float*)d_in[4];
  const int*   cmask = (const int*)d_in[5];

  // ~70 MB total (ws_size ~256 MB per harness fill evidence)
  char* ws = (char*)d_ws;
  bf16* xb    = (bf16*)ws; ws += (size_t)M * E * 2;              // 8 MB
  bf16* wtin  = (bf16*)ws; ws += (size_t)N3 * E * 2;             // 6 MB
  bf16* wtout = (bf16*)ws; ws += (size_t)E * E * 2;              // 2 MB
  bf16* qB    = (bf16*)ws; ws += (size_t)B * H * S * D * 2;      // 8 MB
  bf16* kF    = (bf16*)ws; ws += (size_t)B * H * S * D * 2;      // 8 MB (fragment-major)
  bf16* vF    = (bf16*)ws; ws += (size_t)B * H * S * D * 2;      // 8 MB (fragment-major)
  bf16* ao    = (bf16*)ws; ws += (size_t)M * E * 2;              // 8 MB
  bf16* pO    = (bf16*)ws; ws += (size_t)32 * NSLOT * 128 * D * 2; // 20 MB
  float* pMb  = (float*)ws; ws += (size_t)32 * NSLOT * 128 * 4;    // 640 KB
  float* pLb  = (float*)ws; ws += (size_t)32 * NSLOT * 128 * 4;    // 640 KB

  k_prep<<<4096 + 3072 + 1024, 256, 0, stream>>>(x, xb, W_in, wtin, W_out, wtout);
  k_gemm<0><<<dim3((M / 128) * (N3 / 128)), 256, 0, stream>>>(
      xb, wtin, b_in, nullptr, qB, kF, vF, E, N3);
  k_attn<<<dim3(32, NSLOT), 256, 0, stream>>>(qB, kF, vF, pO, pMb, pLb, cmask);
  k_combine<<<NROWS * 8 / 256, 256, 0, stream>>>(pO, pMb, pLb, ao);
  k_gemm<1><<<dim3((M / 128) * (E / 128)), 256, 0, stream>>>(
      ao, wtout, b_out, (float*)d_out, nullptr, nullptr, nullptr, E, E);
}

// Round 17
// 103.361 us; speedup vs baseline: 1.0482x; 1.0482x over previous
//
#include <hip/hip_runtime.h>
#include <hip/hip_bf16.h>
#include <cmath>

typedef __bf16 bf16;
typedef __attribute__((ext_vector_type(8))) __bf16 bf16x8;
typedef __attribute__((ext_vector_type(4))) __bf16 bf16x4;
typedef __attribute__((ext_vector_type(4))) float f32x4;
typedef __attribute__((ext_vector_type(16))) float f32x16;
typedef unsigned int u32;

constexpr int S  = 2048;
constexpr int E  = 1024;
constexpr int H  = 16;
constexpr int D  = 64;
constexpr int B  = 2;
constexpr int M  = B * S;       // 4096 rows
constexpr int N3 = 3 * E;       // 3072
constexpr int NROWS = B * H * S; // 65536

// graded K-split tables (round-10/15, verified best): 64-key tiles, chunk c has
// nt=2c+2 tiles (causal), P partials, max 11 tiles/block, exactly 32 slots/bh.
__constant__ int P_tab_d[16] = {1,1,1,1,1,2,2,2,2,2,2,3,3,3,3,3};
__constant__ int S_tab_d[16] = {0,1,2,3,4,5,7,9,11,13,15,17,20,23,26,29};
__constant__ int c_ord_d[32] = {15,15,10,10, 15,14,14,14,13,9,9,4,
                                13,13,12,12,8,8, 12,11,11,11,7,7,3,
                                6,6, 5,5,2, 1, 0};
__constant__ int p_ord_d[32] = {1,2,0,1, 0,0,1,2,2,0,1,0,
                                0,1,1,2,0,1, 0,0,1,2,0,1,0,
                                0,1, 0,1,0, 0, 0};

static __device__ __forceinline__ void gload16(const void* g, void* l) {
  __builtin_amdgcn_global_load_lds((const __attribute__((address_space(1))) void*)g,
                                   (__attribute__((address_space(3))) void*)l, 16, 0, 0);
}

static __device__ __forceinline__ u32 pack2(float a, float b) {
  union { bf16 h[2]; u32 u; } r;
  r.h[0] = (bf16)a; r.h[1] = (bf16)b;
  return r.u;
}
typedef union { u32 w[4]; bf16x8 v; } FU;

// ---------- fused prep: cvt x->bf16 | W_in^T | W_out^T ----------
__global__ __launch_bounds__(256) void k_prep(
    const float* __restrict__ x, bf16* __restrict__ xb,
    const float* __restrict__ W_in, bf16* __restrict__ wtin,
    const float* __restrict__ W_out, bf16* __restrict__ wtout)
{
  const int bid = blockIdx.x;
  if (bid < 4096) {
    const int i = (bid * 256 + threadIdx.x) * 4;
    const float4 v = *(const float4*)(x + i);
    bf16x4 o = { (bf16)v.x, (bf16)v.y, (bf16)v.z, (bf16)v.w };
    *(bf16x4*)(xb + i) = o;
  } else {
    __shared__ float t[32][33];
    const float* in;
    bf16* out;
    int R, C, bx, by;
    if (bid < 4096 + 3072) {
      const int b = bid - 4096;
      in = W_in; out = wtin; R = E; C = N3;
      bx = b % (N3 / 32); by = b / (N3 / 32);
    } else {
      const int b = bid - 4096 - 3072;
      in = W_out; out = wtout; R = E; C = E;
      bx = b % (E / 32); by = b / (E / 32);
    }
    const int c0 = bx * 32, r0 = by * 32;
    const int tx = threadIdx.x & 31, ty = threadIdx.x >> 5;
    #pragma unroll
    for (int j = 0; j < 32; j += 8)
      t[ty + j][tx] = in[(size_t)(r0 + ty + j) * C + c0 + tx];
    __syncthreads();
    #pragma unroll
    for (int j = 0; j < 32; j += 8)
      out[(size_t)(c0 + ty + j) * R + r0 + tx] = (bf16)t[tx][ty + j];
  }
}

// ---------- GEMM (round 6/9/10/13, verified) ----------
template<int EPI>
__global__ __launch_bounds__(256) void k_gemm(
    const bf16* __restrict__ A, const bf16* __restrict__ Bt,
    const float* __restrict__ bias, float* __restrict__ outF,
    bf16* __restrict__ oQ, bf16* __restrict__ oK, bf16* __restrict__ oV,
    int Kdim, int Nn)
{
  __shared__ __align__(16) char smem[65536];
  const int tid = threadIdx.x;
  const int lane = tid & 63, w = tid >> 6;
  const int lane15 = lane & 15, quad = lane >> 4;
  const int wm = w >> 1, wn = w & 1;

  const int nbx = Nn >> 7;
  const int nwg = gridDim.x;
  const int bid = blockIdx.x;
  const int swz = (bid & 7) * (nwg >> 3) + (bid >> 3);
  const int bn0 = (swz % nbx) * 128;
  const int bm0 = (swz / nbx) * 128;

  const int so0 = w * 1024 + lane * 16;
  int srow[4], slk[4];
  #pragma unroll
  for (int p = 0; p < 4; ++p) {
    const int o = p * 4096 + so0;
    const int row = o >> 7, cbyte = o & 127;
    srow[p] = row;
    slk[p] = (cbyte ^ ((row & 7) << 4)) >> 1;
  }

  f32x4 acc[4][4] = {};
  const int nkt = Kdim >> 6;

  #pragma unroll
  for (int p = 0; p < 4; ++p) {
    gload16(A  + (size_t)(bm0 + srow[p]) * Kdim + slk[p], smem +         p * 4096 + w * 1024);
    gload16(Bt + (size_t)(bn0 + srow[p]) * Kdim + slk[p], smem + 32768 + p * 4096 + w * 1024);
  }

  #pragma unroll 1
  for (int kt = 0; kt < nkt; ++kt) {
    const int cur = kt & 1;
    __builtin_amdgcn_s_barrier();
    if (kt + 1 < nkt) {
      const int k0 = (kt + 1) << 6;
      const int nb = (cur ^ 1) * 16384;
      #pragma unroll
      for (int p = 0; p < 4; ++p) {
        gload16(A  + (size_t)(bm0 + srow[p]) * Kdim + k0 + slk[p],
                smem + nb +         p * 4096 + w * 1024);
        gload16(Bt + (size_t)(bn0 + srow[p]) * Kdim + k0 + slk[p],
                smem + nb + 32768 + p * 4096 + w * 1024);
      }
      asm volatile("s_waitcnt vmcnt(8)" ::: "memory");
    } else {
      asm volatile("s_waitcnt vmcnt(0)" ::: "memory");
    }
    __builtin_amdgcn_s_barrier();

    const char* cA = smem + cur * 16384;
    const char* cB = smem + 32768 + cur * 16384;
    #pragma unroll
    for (int kk = 0; kk < 2; ++kk) {
      bf16x8 af[4], bfr[4];
      #pragma unroll
      for (int f = 0; f < 4; ++f) {
        const int ra = wm * 64 + f * 16 + lane15;
        af[f] = *(const bf16x8*)(cA + ra * 128 +
                 ((kk * 64 + (quad << 4)) ^ ((ra & 7) << 4)));
        const int rb = wn * 64 + f * 16 + lane15;
        bfr[f] = *(const bf16x8*)(cB + rb * 128 +
                 ((kk * 64 + (quad << 4)) ^ ((rb & 7) << 4)));
      }
      #pragma unroll
      for (int i = 0; i < 4; ++i)
        #pragma unroll
        for (int j = 0; j < 4; ++j)
          acc[i][j] = __builtin_amdgcn_mfma_f32_16x16x32_bf16(af[i], bfr[j], acc[i][j], 0, 0, 0);
    }
  }

  if constexpr (EPI == 1) {
    #pragma unroll
    for (int i = 0; i < 4; ++i)
      #pragma unroll
      for (int j = 0; j < 4; ++j) {
        const int n = bn0 + wn * 64 + j * 16 + lane15;
        const float bv = bias[n];
        #pragma unroll
        for (int r = 0; r < 4; ++r) {
          const int m = bm0 + wm * 64 + i * 16 + quad * 4 + r;
          outF[(size_t)m * E + n] = acc[i][j][r] + bv;
        }
      }
  } else {
    const int which = bn0 >> 10;
    const int b  = bm0 >> 11;
    const int s0 = bm0 & (S - 1);
    const int cn0 = bn0 & (E - 1);
    if (which < 2) {
      __builtin_amdgcn_s_barrier();
      char* lC = smem;
      #pragma unroll
      for (int j = 0; j < 4; ++j) {
        const int n_loc = wn * 64 + j * 16 + lane15;
        const float bv = bias[bn0 + n_loc];
        #pragma unroll
        for (int i = 0; i < 4; ++i)
          #pragma unroll
          for (int r = 0; r < 4; ++r) {
            const int m_loc = wm * 64 + i * 16 + quad * 4 + r;
            *(bf16*)(lC + m_loc * 256 + ((n_loc * 2) ^ ((m_loc & 7) << 4))) =
                (bf16)(acc[i][j][r] + bv);
          }
      }
      __builtin_amdgcn_s_barrier();
      const int h0 = cn0 >> 6;
      #pragma unroll
      for (int it = 0; it < 8; ++it) {
        const int cch = w * 64 + it * 8 + (lane >> 3);
        const int m_loc = cch >> 1, hh = cch & 1, piece = lane & 7;
        const bf16x8 vv = *(const bf16x8*)(lC + m_loc * 256 +
                          ((hh * 128 + piece * 16) ^ ((m_loc & 7) << 4)));
        if (which == 0) {
          *(bf16x8*)(oQ + ((size_t)(b * H + h0 + hh) * S + s0 + m_loc) * D + piece * 8) = vv;
        } else {
          const size_t hb = (size_t)(b * H + h0 + hh) * S * D;
          const int tile = (s0 + m_loc) >> 6;
          const int row = m_loc & 63;
          *(bf16x8*)(oK + hb + (size_t)tile * 4096 + (piece >> 1) * 1024 +
                     (row >> 5) * 512 + (32 * (piece & 1) + (row & 31)) * 8) = vv;
        }
      }
    } else {
      #pragma unroll
      for (int j = 0; j < 4; ++j) {
        const int n_loc = wn * 64 + j * 16 + lane15;
        const int cn = cn0 + n_loc;
        const int hv = cn >> 6, dd = cn & 63;
        const float bv = bias[bn0 + n_loc];
        const size_t hb = (size_t)(b * H + hv) * S * D;
        #pragma unroll
        for (int i = 0; i < 4; ++i) {
          const int scol_g = s0 + wm * 64 + i * 16 + quad * 4;
          const int vtile = scol_g >> 6;
          const int cg = (scol_g & 63) >> 3;
          bf16x4 pk = { (bf16)(acc[i][j][0] + bv), (bf16)(acc[i][j][1] + bv),
                        (bf16)(acc[i][j][2] + bv), (bf16)(acc[i][j][3] + bv) };
          *(bf16x4*)(oV + hb + (size_t)vtile * 4096 + (cg >> 1) * 1024 +
                     (dd >> 5) * 512 + (32 * (cg & 1) + (dd & 31)) * 8 +
                     (quad & 1) * 4) = pk;
        }
      }
    }
  }
}

// ---------- flash attention: round-15 verbatim (best measured) ----------
// KVBLK=64, graded K-split max 11 tiles/block, barrier-free, fragment-major
// K/V global reads, defer-max THR=64 (nat-exp slack 8; combine exact).
__global__ __launch_bounds__(256, 4) void k_attn(
    const bf16* __restrict__ Qb, const bf16* __restrict__ Kf, const bf16* __restrict__ Vf,
    bf16* __restrict__ pO0, bf16* __restrict__ pO1,
    float* __restrict__ pM, float* __restrict__ pL, const int* __restrict__ cmask)
{
  __shared__ float corr_lds[4][32];
  __shared__ float lrow_lds[4][32];

  const int tid = threadIdx.x, lane = tid & 63, w = tid >> 6;
  const int h = lane >> 5, q31 = lane & 31;
  const int bh = blockIdx.x;
  const int yy = blockIdx.y;
  const int c  = c_ord_d[yy];
  const int p  = p_ord_d[yy];
  const int Pc = P_tab_d[c];
  const int sslot = S_tab_d[c] + p;
  const int causal = cmask[0];
  const float S2 = 0.18033688011112042f;  // (1/sqrt(D)) * log2(e)

  const bf16* Qh = Qb + (size_t)bh * S * D;
  const bf16* Kh = Kf + (size_t)bh * S * D;
  const bf16* Vh = Vf + (size_t)bh * S * D;

  const int nt = causal ? (2 * c + 2) : (S / 64);
  const int t0 = (p * nt) / Pc;
  const int t1 = ((p + 1) * nt) / Pc;
  const int q0w = c * 128 + 32 * w;
  const int qg  = q0w + q31;
  const int t1w = causal ? min(t1, ((q0w + 31) >> 6) + 1) : t1;

  bf16x8 qf[4];
  #pragma unroll
  for (int ds = 0; ds < 4; ++ds)
    qf[ds] = *(const bf16x8*)(Qh + (size_t)qg * D + 16 * ds + 8 * h);

  f32x16 o0 = {}, o1 = {};
  float mrun = -INFINITY, lr = 0.f;

  #pragma unroll 1
  for (int t = t0; t < t1w; ++t) {
    const bf16* ktb = Kh + (size_t)t * 4096;
    const bf16* vtb = Vh + (size_t)t * 4096;

    bf16x8 kf0[4], kf1[4];
    #pragma unroll
    for (int ds = 0; ds < 4; ++ds) {
      kf0[ds] = *(const bf16x8*)(ktb + ds * 1024 +       lane * 8);
      kf1[ds] = *(const bf16x8*)(ktb + ds * 1024 + 512 + lane * 8);
    }

    f32x16 s0v = {}, s1v = {};
    __builtin_amdgcn_s_setprio(1);
    #pragma unroll
    for (int ds = 0; ds < 4; ++ds) {
      s0v = __builtin_amdgcn_mfma_f32_32x32x16_bf16(kf0[ds], qf[ds], s0v, 0, 0, 0);
      s1v = __builtin_amdgcn_mfma_f32_32x32x16_bf16(kf1[ds], qf[ds], s1v, 0, 0, 0);
    }
    __builtin_amdgcn_s_setprio(0);

    if (causal && (64 * t + 63 > q0w)) {
      #pragma unroll
      for (int rr = 0; rr < 16; ++rr) {
        const int kg = 64 * t + (rr & 3) + 8 * (rr >> 2) + 4 * h;
        if (kg > qg)      s0v[rr] = -INFINITY;
        if (kg + 32 > qg) s1v[rr] = -INFINITY;
      }
    }

    float a8[8];
    #pragma unroll
    for (int i = 0; i < 8; ++i)
      a8[i] = fmaxf(fmaxf(s0v[i], s0v[i + 8]), fmaxf(s1v[i], s1v[i + 8]));
    float tmax = fmaxf(fmaxf(fmaxf(a8[0], a8[1]), fmaxf(a8[2], a8[3])),
                       fmaxf(fmaxf(a8[4], a8[5]), fmaxf(a8[6], a8[7])));
    tmax = fmaxf(tmax, __shfl_xor(tmax, 32, 64));

    // T13 defer-max: skip rescale while max grows by < 64 score units (e^8)
    const bool nogrow = __all(tmax <= mrun + 64.f);
    const float mnew = nogrow ? mrun : fmaxf(mrun, tmax);
    float corrf = 1.f;
    if (!nogrow) {
      corrf = __builtin_amdgcn_exp2f((mrun - mnew) * S2);
      corr_lds[w][q31] = corrf;
    }
    const float msc = mnew * S2;

    #pragma unroll
    for (int rr = 0; rr < 16; ++rr) {
      s0v[rr] = __builtin_amdgcn_exp2f(__builtin_fmaf(s0v[rr], S2, -msc));
      s1v[rr] = __builtin_amdgcn_exp2f(__builtin_fmaf(s1v[rr], S2, -msc));
    }

    float b8[8];
    #pragma unroll
    for (int i = 0; i < 8; ++i)
      b8[i] = (s0v[i] + s0v[i + 8]) + (s1v[i] + s1v[i + 8]);
    float psum = ((b8[0] + b8[1]) + (b8[2] + b8[3])) + ((b8[4] + b8[5]) + (b8[6] + b8[7]));
    psum += __shfl_xor(psum, 32, 64);
    lr = lr * corrf + psum;
    mrun = mnew;

    u32 pk[8][2];
    #pragma unroll
    for (int jj = 0; jj < 4; ++jj) {
      pk[jj][0]     = pack2(s0v[4 * jj],     s0v[4 * jj + 1]);
      pk[jj][1]     = pack2(s0v[4 * jj + 2], s0v[4 * jj + 3]);
      pk[jj + 4][0] = pack2(s1v[4 * jj],     s1v[4 * jj + 1]);
      pk[jj + 4][1] = pack2(s1v[4 * jj + 2], s1v[4 * jj + 3]);
    }

    if (!nogrow) {
      #pragma unroll
      for (int j = 0; j < 4; ++j) {
        const f32x4 cv = *(const f32x4*)&corr_lds[w][8 * j + 4 * h];
        #pragma unroll
        for (int sr = 0; sr < 4; ++sr) {
          o0[4 * j + sr] *= cv[sr];
          o1[4 * j + sr] *= cv[sr];
        }
      }
    }

    __builtin_amdgcn_s_setprio(1);
    #pragma unroll
    for (int ks = 0; ks < 4; ++ks) {
      u32 a0 = pk[2 * ks][0], b0 = pk[2 * ks + 1][0];
      u32 a1 = pk[2 * ks][1], b1 = pk[2 * ks + 1][1];
      asm volatile("v_permlane32_swap_b32 %0, %1" : "+v"(a0), "+v"(b0));
      asm volatile("v_permlane32_swap_b32 %0, %1" : "+v"(a1), "+v"(b1));
      FU f; f.w[0] = a0; f.w[1] = a1; f.w[2] = b0; f.w[3] = b1;
      const bf16x8 vf0 = *(const bf16x8*)(vtb + ks * 1024 +       lane * 8);
      const bf16x8 vf1 = *(const bf16x8*)(vtb + ks * 1024 + 512 + lane * 8);
      o0 = __builtin_amdgcn_mfma_f32_32x32x16_bf16(f.v, vf0, o0, 0, 0, 0);
      o1 = __builtin_amdgcn_mfma_f32_32x32x16_bf16(f.v, vf1, o1, 0, 0, 0);
    }
    __builtin_amdgcn_s_setprio(0);
  }  // t

  const int slotbase = ((bh & 15) * 32 + sslot) * 128;
  if (h == 0) {
    pM[(size_t)(bh * 32 + sslot) * 128 + 32 * w + q31] = mrun;
    pL[(size_t)(bh * 32 + sslot) * 128 + 32 * w + q31] = lr;
  }
  lrow_lds[w][q31] = lr;
  bf16* po = (bh < 16 ? pO0 : pO1) + (size_t)slotbase * D;
  #pragma unroll
  for (int j = 0; j < 4; ++j) {
    const f32x4 lv = *(const f32x4*)&lrow_lds[w][8 * j + 4 * h];
    #pragma unroll
    for (int sr = 0; sr < 4; ++sr) {
      const int rr = 4 * j + sr;
      const float inv = lv[sr] > 0.f ? 1.0f / lv[sr] : 0.f;
      const int qloc = 32 * w + (rr & 3) + 8 * (rr >> 2) + 4 * h;
      bf16* dst = po + (size_t)qloc * D;
      dst[q31]      = (bf16)(o0[rr] * inv);
      dst[32 + q31] = (bf16)(o1[rr] * inv);
    }
  }
}

// ---------- combine graded partials -> AO[B,S,E] ----------
__global__ __launch_bounds__(256) void k_combine(
    const bf16* __restrict__ pO0, const bf16* __restrict__ pO1,
    const float* __restrict__ pM, const float* __restrict__ pL,
    bf16* __restrict__ AO)
{
  const float S2 = 0.18033688011112042f;
  const int idx = blockIdx.x * 256 + threadIdx.x;
  const int row = idx >> 3, d0 = (idx & 7) * 8;
  const int bh = row >> 11, s = row & 2047;
  const int c = s >> 7, local = s & 127;
  const int Pc = P_tab_d[c], Sc = S_tab_d[c];
  const bf16* pbase = (bh < 16 ? pO0 : pO1);

  float mv[3], lv[3];
  float m = -INFINITY;
  #pragma unroll
  for (int p = 0; p < 3; ++p) {
    if (p < Pc) {
      mv[p] = pM[(size_t)(bh * 32 + Sc + p) * 128 + local];
      lv[p] = pL[(size_t)(bh * 32 + Sc + p) * 128 + local];
      m = fmaxf(m, mv[p]);
    }
  }
  float wsum = 0.f, wv[3];
  #pragma unroll
  for (int p = 0; p < 3; ++p) {
    wv[p] = 0.f;
    if (p < Pc && lv[p] > 0.f) {
      wv[p] = lv[p] * __builtin_amdgcn_exp2f((mv[p] - m) * S2);
      wsum += wv[p];
    }
  }
  const float inv = 1.0f / wsum;
  float acc[8] = {};
  #pragma unroll
  for (int p = 0; p < 3; ++p) {
    if (p < Pc) {
      const bf16x8 a = *(const bf16x8*)(pbase +
          ((size_t)((bh & 15) * 32 + Sc + p) * 128 + local) * D + d0);
      #pragma unroll
      for (int i = 0; i < 8; ++i)
        acc[i] += wv[p] * (float)a[i];
    }
  }
  bf16x8 o;
  #pragma unroll
  for (int i = 0; i < 8; ++i)
    o[i] = (bf16)(acc[i] * inv);
  const int bb = row >> 15, hh = (row >> 11) & 15;
  *(bf16x8*)(AO + ((size_t)(bb * S + s)) * E + hh * D + d0) = o;
}

extern "C" void kernel_launch(void* const* d_in, const int* in_sizes, int n_in,
                              void* d_out, int out_size, void* d_ws, size_t ws_size,
                              hipStream_t stream) {
  (void)in_sizes; (void)n_in; (void)out_size; (void)ws_size;
  const float* x     = (const float*)d_in[0];
  const float* W_in  = (const float*)d_in[1];
  const float* b_in  = (const float*)d_in[2];
  const float* W_out = (const float*)d_in[3];
  const float* b_out = (const float*)d_in[4];
  const int*   cmask = (const int*)d_in[5];

  // 57 MB total (round-6/9/10/13/15 proven envelope, byte-identical layout)
  char* ws = (char*)d_ws;
  bf16* xb    = (bf16*)ws; ws += (size_t)M * E * 2;          // pO half 0 overlays after gemm0
  bf16* wtin  = (bf16*)ws; ws += (size_t)N3 * E * 2;
  bf16* wtout = (bf16*)ws; ws += (size_t)E * E * 2;
  bf16* qB    = (bf16*)ws; ws += (size_t)B * H * S * D * 2;
  bf16* kF    = (bf16*)ws; ws += (size_t)B * H * S * D * 2;  // fragment-major
  bf16* vF    = (bf16*)ws; ws += (size_t)B * H * S * D * 2;  // fragment-major
  bf16* ao    = (bf16*)ws; ws += (size_t)M * E * 2;
  bf16* pO1   = (bf16*)ws; ws += (size_t)NROWS * D * 2;      // pO half 1
  float* pMb  = (float*)ws; ws += (size_t)2 * NROWS * 4;
  float* pLb  = (float*)ws; ws += (size_t)2 * NROWS * 4;
  bf16* pO0   = xb;

  k_prep<<<4096 + 3072 + 1024, 256, 0, stream>>>(x, xb, W_in, wtin, W_out, wtout);
  k_gemm<0><<<dim3((M / 128) * (N3 / 128)), 256, 0, stream>>>(
      xb, wtin, b_in, nullptr, qB, kF, vF, E, N3);
  k_attn<<<dim3(32, 32), 256, 0, stream>>>(qB, kF, vF, pO0, pO1, pMb, pLb, cmask);
  k_combine<<<NROWS * 8 / 256, 256, 0, stream>>>(pO0, pO1, pMb, pLb, ao);
  k_gemm<1><<<dim3((M / 128) * (E / 128)), 256, 0, stream>>>(
      ao, wtout, b_out, (float*)d_out, nullptr, nullptr, nullptr, E, E);
}